// Round 10
// baseline (488.068 us; speedup 1.0000x reference)
//
#include <hip/hip_runtime.h>

typedef unsigned int u32;
typedef unsigned short u16;
typedef __attribute__((ext_vector_type(4))) float f32x4;
typedef __attribute__((ext_vector_type(4))) int i32x4;
typedef __attribute__((ext_vector_type(2))) int i32x2;
typedef __attribute__((ext_vector_type(8))) short s16x8;

#define N_NODES 8192
#define F_DIM 512

#define BARRIER_NOVM() asm volatile("s_waitcnt lgkmcnt(0)\ns_barrier" ::: "memory")

__device__ __forceinline__ int fm_swz(int m) {
    return ((m >> 2) & 7) ^ ((m & 3) << 1);
}

__device__ __forceinline__ u16 f2bf(float x) {
    u32 u = __builtin_bit_cast(u32, x);
    u = (u + 0x7FFFu + ((u >> 16) & 1u)) >> 16;
    return (u16)u;
}

__device__ __forceinline__ float bf2f(u16 b) {
    u32 u = ((u32)b) << 16;
    return __builtin_bit_cast(float, u);
}

__device__ __forceinline__ void glds16(const u16* g, u16* l) {
    __builtin_amdgcn_global_load_lds((const __attribute__((address_space(1))) u32*)g,
                                     (__attribute__((address_space(3))) u32*)l, 16, 0, 0);
}

// ---------------- kM ----------------
// blocks 0..255   : k1  Yt[f][i] = bf16(sum_c W[c][f]*X[i][c])
// blocks 256..2303: kT  bit-transpose. Block = (i-word w, j-eighth). Per thread:
//   32 INDEPENDENT i32x4 loads (two 16-deep batches, 16 KB in flight per wave)
//   -> one i32x4 store of packed bit-words. Max memory-level parallelism.
__global__ __launch_bounds__(256, 4)
void kM(const int* __restrict__ adj, const float* __restrict__ X, const float* __restrict__ W,
        u32* __restrict__ Atw, u16* __restrict__ Yt) {
    __shared__ __align__(16) u16 SH[16384];  // k1 branch only

    const int tid = threadIdx.x;

    if (blockIdx.x >= 256) {
        const int b = blockIdx.x - 256;
        const int w = b >> 3;             // i-word (256)
        const int j0 = (b & 7) * 1024;    // j-eighth
        const int* base = adj + (size_t)w * 32 * N_NODES + j0 + tid * 4;

        u32 wacc[4] = {0, 0, 0, 0};
        i32x4 cur[16];
#pragma unroll
        for (int r = 0; r < 16; ++r)
            cur[r] = *(const i32x4*)(base + (size_t)r * N_NODES);
#pragma unroll
        for (int r = 0; r < 16; ++r)
#pragma unroll
            for (int e = 0; e < 4; ++e)
                wacc[e] |= ((u32)cur[r][e]) << r;
#pragma unroll
        for (int r = 0; r < 16; ++r)
            cur[r] = *(const i32x4*)(base + (size_t)(16 + r) * N_NODES);
#pragma unroll
        for (int r = 0; r < 16; ++r)
#pragma unroll
            for (int e = 0; e < 4; ++e)
                wacc[e] |= ((u32)cur[r][e]) << (16 + r);

        i32x4 v = {(int)wacc[0], (int)wacc[1], (int)wacc[2], (int)wacc[3]};
        *(i32x4*)(Atw + (size_t)w * N_NODES + j0 + tid * 4) = v;
        return;
    }

    // ---- k1 ----
    u16* Wl = SH;          // 128 x 64
    u16* Xl = SH + 8192;   // 128 x 64

    const int bid = blockIdx.x;
    const int lane = tid & 63;
    const int wave = tid >> 6;
    const int wm = wave >> 1, wn = wave & 1;
    const int col = lane & 15, quad = lane >> 4;

    const int f0 = (bid & 3) * 128;
    const int i0 = (bid >> 2) * 128;

    const int cgrp = tid & 31;
    const int kk   = tid >> 5;
    const int xcq  = tid & 15;
    const int xig  = tid >> 4;

    f32x4 wr[8], xr[8];
    {
        const float* wp = W + (size_t)(kk * 8) * F_DIM + f0 + cgrp * 4;
        const float* xp = X + (size_t)(i0 + xig * 8) * F_DIM + xcq * 4;
#pragma unroll
        for (int r = 0; r < 8; ++r) wr[r] = *(const f32x4*)(wp + (size_t)r * F_DIM);
#pragma unroll
        for (int r = 0; r < 8; ++r) xr[r] = *(const f32x4*)(xp + (size_t)r * F_DIM);
    }

    f32x4 acc[4][4] = {};

    for (int s = 0; s < 8; ++s) {
        BARRIER_NOVM();
#pragma unroll
        for (int mm = 0; mm < 4; ++mm) {
            int m = cgrp * 4 + mm;
            u32 q0 = ((u32)f2bf(wr[1][mm]) << 16) | f2bf(wr[0][mm]);
            u32 q1 = ((u32)f2bf(wr[3][mm]) << 16) | f2bf(wr[2][mm]);
            u32 q2 = ((u32)f2bf(wr[5][mm]) << 16) | f2bf(wr[4][mm]);
            u32 q3 = ((u32)f2bf(wr[7][mm]) << 16) | f2bf(wr[6][mm]);
            i32x4 v = {(int)q0, (int)q1, (int)q2, (int)q3};
            *(i32x4*)&Wl[m * 64 + ((kk ^ fm_swz(m)) << 3)] = v;
        }
#pragma unroll
        for (int r = 0; r < 8; ++r) {
            int row = xig * 8 + r;
            u32 a = ((u32)f2bf(xr[r][1]) << 16) | f2bf(xr[r][0]);
            u32 b = ((u32)f2bf(xr[r][3]) << 16) | f2bf(xr[r][2]);
            int kc = xcq >> 1, half = xcq & 1;
            i32x2 v = {(int)a, (int)b};
            *(i32x2*)&Xl[row * 64 + ((kc ^ (row & 7)) << 3) + half * 4] = v;
        }
        BARRIER_NOVM();
        if (s + 1 < 8) {
            int c0 = (s + 1) * 64;
            const float* wp = W + (size_t)(c0 + kk * 8) * F_DIM + f0 + cgrp * 4;
            const float* xp = X + (size_t)(i0 + xig * 8) * F_DIM + c0 + xcq * 4;
#pragma unroll
            for (int r = 0; r < 8; ++r) wr[r] = *(const f32x4*)(wp + (size_t)r * F_DIM);
#pragma unroll
            for (int r = 0; r < 8; ++r) xr[r] = *(const f32x4*)(xp + (size_t)r * F_DIM);
        }
#pragma unroll
        for (int s2 = 0; s2 < 2; ++s2) {
            s16x8 af[4], bfr[4];
#pragma unroll
            for (int mi = 0; mi < 4; ++mi) {
                int m = wm * 64 + mi * 16 + col;
                int kc = s2 * 4 + quad;
                af[mi] = *(const s16x8*)&Wl[m * 64 + ((kc ^ fm_swz(m)) << 3)];
            }
#pragma unroll
            for (int ni = 0; ni < 4; ++ni) {
                int rr = wn * 64 + ni * 16 + col;
                int kc = s2 * 4 + quad;
                bfr[ni] = *(const s16x8*)&Xl[rr * 64 + ((kc ^ (rr & 7)) << 3)];
            }
#pragma unroll
            for (int mi = 0; mi < 4; ++mi)
#pragma unroll
                for (int ni = 0; ni < 4; ++ni)
                    acc[mi][ni] = __builtin_amdgcn_mfma_f32_16x16x32_bf16(af[mi], bfr[ni],
                                                                          acc[mi][ni], 0, 0, 0);
        }
    }

#pragma unroll
    for (int mi = 0; mi < 4; ++mi)
#pragma unroll
        for (int r = 0; r < 4; ++r) {
            int f = f0 + wm * 64 + mi * 16 + quad * 4 + r;
#pragma unroll
            for (int ni = 0; ni < 4; ++ni) {
                int i = i0 + wn * 64 + ni * 16 + col;
                Yt[(size_t)f * N_NODES + i] = f2bf(acc[mi][ni][r]);
            }
        }
}

// ---------------- kD: deg[j] = sum_w popc(Atw[w][j]) ----------------
__global__ __launch_bounds__(256, 8)
void kD(const u32* __restrict__ Atw, int* __restrict__ deg) {
    const int j = blockIdx.x * 256 + threadIdx.x;
    int s = 0;
#pragma unroll 8
    for (int w = 0; w < 256; ++w)
        s += __popc(Atw[(size_t)w * N_NODES + j]);
    deg[j] = s;
}

// ---------------- Kernel 2: bf16 GEMM with in-loop A-bit expansion ----------------
// Swizzle: bid = stripe*16 + f_idx*4 + kq -> all 64 stripes of one (f,kq) share bid%8
// (same XCD). Per-XCD working set: 2 Yt slices (1 MB) + Atw kq-slice (2 MB) fits 4 MB L2,
// so the 64x B-tile reuse is served by L2, not L3.
__global__ __launch_bounds__(256, 4)
void k2_gemm(const u32* __restrict__ Atw, const u16* __restrict__ Yt,
             u16* __restrict__ parts) {
    __shared__ __align__(16) u16 As[128 * 64];
    __shared__ __align__(16) u16 Bs[128 * 64];

    const int tid = threadIdx.x, lane = tid & 63, wave = tid >> 6;
    const int wm = wave >> 1, wn = wave & 1;
    const int col = lane & 15, quad = lane >> 4;

    const int stripe = blockIdx.x >> 4;
    const int f_idx  = (blockIdx.x >> 2) & 3;
    const int kq     = blockIdx.x & 3;
    const int j0 = stripe * 128, f0 = f_idx * 128, ibase = kq * 2048;
    u16* __restrict__ part = parts + (size_t)kq * N_NODES * F_DIM;

    const int rowl = lane >> 3;
    const int kc = (lane & 7) ^ rowl;

    const int m_up = tid & 127;   // unpack: j-row this thread owns
    const int sh   = tid >> 7;    // unpack: which of the 2 k-words

    f32x4 acc[4][4] = {};

    u32 r = Atw[(size_t)(kq * 64 + sh) * N_NODES + j0 + m_up];

    for (int s = 0; s < 32; ++s) {
        const int ik = ibase + s * 64;
        BARRIER_NOVM();  // all waves done with mfma(s-1); As/Bs free (lgkm only)
#pragma unroll
        for (int gg = 0; gg < 4; ++gg) {
            const int g = wave * 4 + gg;
            glds16(Yt + (size_t)(f0 + g * 8 + rowl) * N_NODES + ik + kc * 8, &Bs[g * 512]);
        }
        {
            u32 wv = r;
#pragma unroll
            for (int q = 0; q < 4; ++q) {
                u32 bb = (wv >> (q * 8)) & 0xFFu;
                u32 w0 = ((bb & 1u) * 0x3F80u) | ((bb & 2u) * 0x1FC00000u);
                u32 w1 = (((bb >> 2) & 1u) * 0x3F80u) | (((bb >> 2) & 2u) * 0x1FC00000u);
                u32 w2 = (((bb >> 4) & 1u) * 0x3F80u) | (((bb >> 4) & 2u) * 0x1FC00000u);
                u32 w3 = (((bb >> 6) & 1u) * 0x3F80u) | (((bb >> 6) & 2u) * 0x1FC00000u);
                int kcs = sh * 4 + q;
                i32x4 v = {(int)w0, (int)w1, (int)w2, (int)w3};
                *(i32x4*)&As[m_up * 64 + ((kcs ^ fm_swz(m_up)) << 3)] = v;
            }
        }
        {
            int sn = (s + 1 < 32) ? (s + 1) : 31;
            r = Atw[(size_t)(kq * 64 + sn * 2 + sh) * N_NODES + j0 + m_up];
        }
        __syncthreads();  // drains glds (B ready) + lgkm (As writes visible)
#pragma unroll
        for (int s2 = 0; s2 < 2; ++s2) {
            s16x8 af[4], bfr[4];
#pragma unroll
            for (int mi = 0; mi < 4; ++mi) {
                int m = wm * 64 + mi * 16 + col;
                int k2i = s2 * 4 + quad;
                af[mi] = *(const s16x8*)&As[m * 64 + ((k2i ^ fm_swz(m)) << 3)];
            }
#pragma unroll
            for (int ni = 0; ni < 4; ++ni) {
                int rr = wn * 64 + ni * 16 + col;
                int k2i = s2 * 4 + quad;
                bfr[ni] = *(const s16x8*)&Bs[rr * 64 + ((k2i ^ (rr & 7)) << 3)];
            }
#pragma unroll
            for (int mi = 0; mi < 4; ++mi)
#pragma unroll
                for (int ni = 0; ni < 4; ++ni)
                    acc[mi][ni] = __builtin_amdgcn_mfma_f32_16x16x32_bf16(af[mi], bfr[ni],
                                                                          acc[mi][ni], 0, 0, 0);
        }
    }

#pragma unroll
    for (int mi = 0; mi < 4; ++mi)
#pragma unroll
        for (int r2 = 0; r2 < 4; ++r2) {
            int jl = wm * 64 + mi * 16 + quad * 4 + r2;
            size_t ob = (size_t)(j0 + jl) * F_DIM + f0 + wn * 64;
#pragma unroll
            for (int ni = 0; ni < 4; ++ni)
                part[ob + ni * 16 + col] = f2bf(acc[mi][ni][r2]);
        }
}

// ---------------- Kernel 3: out = relu( rsqrt(max(deg,1)) * sum4(parts) ) ----------------
__global__ __launch_bounds__(256, 4)
void k3b(const u16* __restrict__ parts, const int* __restrict__ deg,
         float* __restrict__ out) {
    int idx = blockIdx.x * 256 + threadIdx.x;  // 8 f per thread
    int j = idx >> 6;
    int c = (idx & 63) * 8;
    size_t off = (size_t)j * F_DIM + c;
    const size_t PS = (size_t)N_NODES * F_DIM;
    s16x8 a = *(const s16x8*)(parts + off);
    s16x8 b = *(const s16x8*)(parts + PS + off);
    s16x8 cc = *(const s16x8*)(parts + 2 * PS + off);
    s16x8 d = *(const s16x8*)(parts + 3 * PS + off);
    float nv = rsqrtf(fmaxf((float)deg[j], 1.0f));
    f32x4 v0, v1;
#pragma unroll
    for (int t = 0; t < 4; ++t) {
        float s = bf2f((u16)a[t]) + bf2f((u16)b[t]) + bf2f((u16)cc[t]) + bf2f((u16)d[t]);
        v0[t] = fmaxf(s * nv, 0.0f);
    }
#pragma unroll
    for (int t = 0; t < 4; ++t) {
        float s = bf2f((u16)a[4 + t]) + bf2f((u16)b[4 + t]) + bf2f((u16)cc[4 + t]) + bf2f((u16)d[4 + t]);
        v1[t] = fmaxf(s * nv, 0.0f);
    }
    *(f32x4*)(out + off) = v0;
    *(f32x4*)(out + off + 4) = v1;
}

extern "C" void kernel_launch(void* const* d_in, const int* in_sizes, int n_in,
                              void* d_out, int out_size, void* d_ws, size_t ws_size,
                              hipStream_t stream) {
    (void)in_sizes; (void)n_in; (void)out_size; (void)ws_size;
    const float* X = (const float*)d_in[0];
    const int* adj = (const int*)d_in[1];
    const float* W = (const float*)d_in[2];
    float* out = (float*)d_out;
    char* w = (char*)d_ws;

    // ws: Atw(bits) 8Mi | Yt 8Mi | parts(bf16 x4) 32Mi | deg 32K
    u32* Atw = (u32*)w;
    u16* Yt = (u16*)(w + ((size_t)8 << 20));
    u16* parts = (u16*)(w + ((size_t)16 << 20));
    int* deg = (int*)(w + ((size_t)48 << 20));

    kM<<<dim3(2304), dim3(256), 0, stream>>>(adj, X, W, Atw, Yt);
    kD<<<dim3(32), dim3(256), 0, stream>>>(Atw, deg);
    k2_gemm<<<dim3(1024), dim3(256), 0, stream>>>(Atw, Yt, parts);
    k3b<<<dim3(2048), dim3(256), 0, stream>>>(parts, deg, out);
}